// Round 3
// baseline (107.843 us; speedup 1.0000x reference)
//
#include <hip/hip_runtime.h>

// IF neuron: v += x[t]; out = (v >= TH) ? TH : 0; v -= out;  over T=4 steps.
// x: [T=4, B=32, H=512, W=1024] fp32. Streaming, memory-bound.
// 536.9 MB total HBM traffic -> ~85 us at the 6.29 TB/s copy ceiling.
//
// R2 -> R3 changes (post-mortem: nt + grid-stride were neutral/negative):
//  - revert nontemporal, revert grid-stride (R1 direct indexing was faster)
//  - each thread owns 2 consecutive float4 (32 B/lane/stream): 8 outstanding
//    loads before the first dependent op, 2 KiB contiguous per wave per
//    stream -> better HBM row locality, half the VMEM instruction count.

#define TH 1.0f

typedef float f32x4 __attribute__((ext_vector_type(4)));

__device__ __forceinline__ f32x4 spike4(const f32x4& v) {
    f32x4 o;
    o.x = (v.x >= TH) ? TH : 0.f;
    o.y = (v.y >= TH) ? TH : 0.f;
    o.z = (v.z >= TH) ? TH : 0.f;
    o.w = (v.w >= TH) ? TH : 0.f;
    return o;
}

__global__ __launch_bounds__(256) void IFNeuron_90048284328050_kernel(
    const f32x4* __restrict__ x, f32x4* __restrict__ out, int nvec) {
    // each thread handles float4 indices 2*tid and 2*tid+1 in every timestep
    size_t i = ((size_t)blockIdx.x * blockDim.x + threadIdx.x) * 2;
    const size_t nv = (size_t)nvec;
    if (i >= nv) return;

    // 8 independent loads issued back-to-back (8 outstanding VMEM)
    f32x4 x0a = x[i],          x0b = x[i + 1];
    f32x4 x1a = x[nv + i],     x1b = x[nv + i + 1];
    f32x4 x2a = x[2 * nv + i], x2b = x[2 * nv + i + 1];
    f32x4 x3a = x[3 * nv + i], x3b = x[3 * nv + i + 1];

    f32x4 va = x0a, vb = x0b;
    f32x4 o0a = spike4(va), o0b = spike4(vb);
    va = va - o0a + x1a;  vb = vb - o0b + x1b;
    f32x4 o1a = spike4(va), o1b = spike4(vb);
    va = va - o1a + x2a;  vb = vb - o1b + x2b;
    f32x4 o2a = spike4(va), o2b = spike4(vb);
    va = va - o2a + x3a;  vb = vb - o2b + x3b;
    f32x4 o3a = spike4(va), o3b = spike4(vb);

    out[i] = o0a;          out[i + 1] = o0b;
    out[nv + i] = o1a;     out[nv + i + 1] = o1b;
    out[2 * nv + i] = o2a; out[2 * nv + i + 1] = o2b;
    out[3 * nv + i] = o3a; out[3 * nv + i + 1] = o3b;
}

extern "C" void kernel_launch(void* const* d_in, const int* in_sizes, int n_in,
                              void* d_out, int out_size, void* d_ws, size_t ws_size,
                              hipStream_t stream) {
    const f32x4* x = (const f32x4*)d_in[0];
    f32x4* out = (f32x4*)d_out;

    const int T = 4;
    int total = in_sizes[0];            // 67,108,864 floats
    int nvec = (total / T) / 4;         // 4,194,304 float4 per timestep

    int block = 256;
    int threads_needed = nvec / 2;      // 2,097,152 (2 float4 per thread)
    int grid = (threads_needed + block - 1) / block;  // 8192 blocks
    IFNeuron_90048284328050_kernel<<<grid, block, 0, stream>>>(x, out, nvec);
}

// Round 4
// 104.697 us; speedup vs baseline: 1.0300x; 1.0300x over previous
//
#include <hip/hip_runtime.h>

// IF neuron: v += x[t]; out = (v >= TH) ? TH : 0; v -= out;  over T=4 steps.
// x: [T=4, B=32, H=512, W=1024] fp32. Streaming, memory-bound.
// 536.9 MB total HBM traffic -> ~85 us at the 6.29 TB/s copy ceiling.
//
// R3 -> R4 (post-mortem: R3's i=2*tid de-coalesced every load, 32B lane
// stride). This round: block-chunked 2x float4 per thread —
//   block owns a contiguous 512-float4 chunk; thread reads chunk[tid] and
//   chunk[tid+256]. Every load instruction remains perfectly lane-contiguous
//   (1 KiB/wave/instr) AND each thread has 8 loads in flight before the
//   first dependent op. Isolates MLP from coalescing.

#define TH 1.0f

typedef float f32x4 __attribute__((ext_vector_type(4)));

__device__ __forceinline__ f32x4 spike4(const f32x4& v) {
    f32x4 o;
    o.x = (v.x >= TH) ? TH : 0.f;
    o.y = (v.y >= TH) ? TH : 0.f;
    o.z = (v.z >= TH) ? TH : 0.f;
    o.w = (v.w >= TH) ? TH : 0.f;
    return o;
}

__global__ __launch_bounds__(256) void IFNeuron_90048284328050_kernel(
    const f32x4* __restrict__ x, f32x4* __restrict__ out, int nvec) {
    const size_t nv = (size_t)nvec;
    // block-contiguous chunk: 512 float4 per block per timestep
    size_t base = (size_t)blockIdx.x * 512 + threadIdx.x;
    size_t ia = base;          // lane-contiguous
    size_t ib = base + 256;    // lane-contiguous, +4 KiB

    // 8 independent, fully-coalesced loads in flight
    f32x4 x0a = x[ia],          x0b = x[ib];
    f32x4 x1a = x[nv + ia],     x1b = x[nv + ib];
    f32x4 x2a = x[2 * nv + ia], x2b = x[2 * nv + ib];
    f32x4 x3a = x[3 * nv + ia], x3b = x[3 * nv + ib];

    f32x4 va = x0a, vb = x0b;
    f32x4 o0a = spike4(va), o0b = spike4(vb);
    va = va - o0a + x1a;  vb = vb - o0b + x1b;
    f32x4 o1a = spike4(va), o1b = spike4(vb);
    va = va - o1a + x2a;  vb = vb - o1b + x2b;
    f32x4 o2a = spike4(va), o2b = spike4(vb);
    va = va - o2a + x3a;  vb = vb - o2b + x3b;
    f32x4 o3a = spike4(va), o3b = spike4(vb);

    out[ia] = o0a;          out[ib] = o0b;
    out[nv + ia] = o1a;     out[nv + ib] = o1b;
    out[2 * nv + ia] = o2a; out[2 * nv + ib] = o2b;
    out[3 * nv + ia] = o3a; out[3 * nv + ib] = o3b;
}

extern "C" void kernel_launch(void* const* d_in, const int* in_sizes, int n_in,
                              void* d_out, int out_size, void* d_ws, size_t ws_size,
                              hipStream_t stream) {
    const f32x4* x = (const f32x4*)d_in[0];
    f32x4* out = (f32x4*)d_out;

    const int T = 4;
    int total = in_sizes[0];            // 67,108,864 floats
    int nvec = (total / T) / 4;         // 4,194,304 float4 per timestep

    int block = 256;
    int grid = nvec / 512;              // 8192 blocks, 512 float4/block/timestep
    IFNeuron_90048284328050_kernel<<<grid, block, 0, stream>>>(x, out, nvec);
}

// Round 5
// 104.178 us; speedup vs baseline: 1.0352x; 1.0050x over previous
//
#include <hip/hip_runtime.h>

// IF neuron: v += x[t]; out = (v >= TH) ? TH : 0; v -= out;  over T=4 steps.
// x: [T=4, B=32, H=512, W=1024] fp32.  Output same shape/dtype.
// Per-spatial-element recurrence -> one thread owns 4 consecutive spatial
// elements (float4), keeps v in registers, loops over T.
//
// FINAL (revert to R1, the empirical optimum at 100.4 us = 5.35 TB/s):
//  - traffic is minimal: 256 MiB read + 256 MiB write, each byte touched once
//  - 16 B/lane fully-coalesced loads/stores
//  - 1 float4/thread maximizes wave count; R2 (nt+grid-stride), R3
//    (2x/thread strided), R4 (2x/thread chunked) all regressed 2-7% --
//    wave-level TLP saturates HBM; extra per-thread MLP only hurts.

#define TH 1.0f

__global__ __launch_bounds__(256) void IFNeuron_90048284328050_kernel(
    const float4* __restrict__ x, float4* __restrict__ out, int nvec) {
    int i = blockIdx.x * blockDim.x + threadIdx.x;
    if (i >= nvec) return;

    float vx = 0.f, vy = 0.f, vz = 0.f, vw = 0.f;
#pragma unroll
    for (int t = 0; t < 4; ++t) {
        float4 xt = x[(size_t)t * nvec + i];
        vx += xt.x; vy += xt.y; vz += xt.z; vw += xt.w;
        float4 o;
        o.x = (vx >= TH) ? TH : 0.f;
        o.y = (vy >= TH) ? TH : 0.f;
        o.z = (vz >= TH) ? TH : 0.f;
        o.w = (vw >= TH) ? TH : 0.f;
        vx -= o.x; vy -= o.y; vz -= o.z; vw -= o.w;
        out[(size_t)t * nvec + i] = o;
    }
}

extern "C" void kernel_launch(void* const* d_in, const int* in_sizes, int n_in,
                              void* d_out, int out_size, void* d_ws, size_t ws_size,
                              hipStream_t stream) {
    const float4* x = (const float4*)d_in[0];
    float4* out = (float4*)d_out;

    const int T = 4;
    int total = in_sizes[0];            // 67,108,864 floats
    int nspatial = total / T;           // 16,777,216
    int nvec = nspatial / 4;            // 4,194,304 float4 per timestep

    int block = 256;
    int grid = (nvec + block - 1) / block;
    IFNeuron_90048284328050_kernel<<<grid, block, 0, stream>>>(x, out, nvec);
}